// Round 4
// baseline (333.367 us; speedup 1.0000x reference)
//
#include <hip/hip_runtime.h>
#include <hip/hip_bf16.h>
#include <hip/hip_cooperative_groups.h>

// Ensemble SRN: 8 sub-models (2x2x2 octants), MLP 3->128->128->128->1, ReLU.
// R4: single cooperative kernel with occupancy-clamped grid + checked launch;
// falls back to the validated R2 3-node pipeline if coop launch fails.
// ws: [0, 32KB)   cntG[G][8] (coop)  /  cursors[8] (fallback)
//     [32KB, +4*N*8)  perm  (coop uses first N ints; fallback uses 8 segments)
//     [.., +256KB)    Wt1 bf16 [8][128][128]  (transposed [n][k])
//     [.., +256KB)    Wt2 bf16 [8][128][128]

#define HDIM 128
#define LDSH 136      // padded LDS stride (bf16): 272B rows
#define TILE 64
#define NMODEL 8
#define MAXG 1024
#define TILES_X 272   // fallback main grid.x

namespace cg = cooperative_groups;

typedef __bf16 bf16x8 __attribute__((ext_vector_type(8)));
typedef __bf16 bf16x4 __attribute__((ext_vector_type(4)));
typedef float  f32x4  __attribute__((ext_vector_type(4)));

__device__ __forceinline__ int model_of(float x0, float x1, float x2) {
  // match reference: u=(x+1)/(2+1e-6); cell=int(u_flipped*2); idx=c0+2c1+4c2
  const float den = 2.000001f;
  float u0 = (x0 + 1.0f) / den;
  float u1 = (x1 + 1.0f) / den;
  float u2 = (x2 + 1.0f) / den;
  int c0 = (int)(u2 * 2.0f);
  int c1 = (int)(u1 * 2.0f);
  int c2 = (int)(u0 * 2.0f);
  return c0 + (c1 << 1) + (c2 << 2);
}

// GEMM layer: hOut = relu(hIn @ W + b), [64x128]x[128x128] bf16 MFMA.
// wave w owns col-tiles {2w,2w+1}; bias read from global (L1-hot).
__device__ __forceinline__ void gemm_relu(const __bf16* __restrict__ hIn,
                                          __bf16* __restrict__ hOut,
                                          const __bf16* __restrict__ Wt,
                                          const float* __restrict__ bias,
                                          int wave, int l16, int quad)
{
  const int n0 = wave * 32;
  f32x4 acc[4][2] = {};
  #pragma unroll
  for (int kk = 0; kk < 4; ++kk) {
    const int kOff = kk * 32 + quad * 8;
    bf16x8 bv0 = *(const bf16x8*)(Wt + (n0 + l16) * HDIM + kOff);
    bf16x8 bv1 = *(const bf16x8*)(Wt + (n0 + 16 + l16) * HDIM + kOff);
    #pragma unroll
    for (int r = 0; r < 4; ++r) {
      bf16x8 av = *(const bf16x8*)(hIn + (r * 16 + l16) * LDSH + kOff);
      acc[r][0] = __builtin_amdgcn_mfma_f32_16x16x32_bf16(av, bv0, acc[r][0], 0, 0, 0);
      acc[r][1] = __builtin_amdgcn_mfma_f32_16x16x32_bf16(av, bv1, acc[r][1], 0, 0, 0);
    }
  }
  const float bv0 = bias[n0 + l16];
  const float bv1 = bias[n0 + 16 + l16];
  #pragma unroll
  for (int r = 0; r < 4; ++r) {
    #pragma unroll
    for (int c = 0; c < 2; ++c) {
      const int n = n0 + c * 16 + l16;
      const float bb = c ? bv1 : bv0;
      #pragma unroll
      for (int i = 0; i < 4; ++i) {
        const int row = r * 16 + quad * 4 + i;   // C/D: col=lane&15, row=quad*4+reg
        float v = acc[r][c][i] + bb;
        hOut[row * LDSH + n] = (__bf16)fmaxf(v, 0.0f);
      }
    }
  }
}

// ================= cooperative fused kernel =================
__global__ __launch_bounds__(256, 4)
void srn_fused(const float* __restrict__ x,
               const float* __restrict__ W0, const float* __restrict__ b0,
               const float* __restrict__ W1, const float* __restrict__ b1,
               const float* __restrict__ W2, const float* __restrict__ b2,
               const float* __restrict__ W3, const float* __restrict__ b3,
               const float* __restrict__ mins, const float* __restrict__ maxs,
               int* __restrict__ cntG, int* __restrict__ perm,
               __bf16* __restrict__ Wt1, __bf16* __restrict__ Wt2,
               float* __restrict__ out, int N)
{
  __shared__ __align__(16) __bf16 hA[TILE * LDSH];   // also transpose scratch
  __shared__ __align__(16) __bf16 hB[TILE * LDSH];
  __shared__ float xs[TILE][3];
  __shared__ int   pid[TILE];
  __shared__ int lc[NMODEL];
  __shared__ int pre_l[NMODEL], tot_l[NMODEL], gb_l[NMODEL], tstart_l[NMODEL + 1];

  const int b   = blockIdx.x;
  const int G   = gridDim.x;
  const int tid = threadIdx.x;
  cg::grid_group grid = cg::this_grid();

  // ---- Phase A: weight transpose (blocks 0..63) + per-block histogram ----
  if (b < 64) {
    float (*tp)[65] = (float(*)[65])hA;   // overlay; 16640B < 17408B
    const int m   = b >> 3;
    const int r2  = b & 7;
    const int mat = r2 >> 2;
    const int ti  = (r2 >> 1) & 1;
    const int tj  = r2 & 1;
    const float* src = (mat ? W2 : W1) + m * HDIM * HDIM;
    __bf16*      dst = (mat ? Wt2 : Wt1) + m * HDIM * HDIM;
    #pragma unroll
    for (int it = 0; it < 16; ++it) {
      const int rr = (tid >> 6) + it * 4, cc = tid & 63;
      tp[rr][cc] = src[(ti * 64 + rr) * HDIM + tj * 64 + cc];
    }
    __syncthreads();
    #pragma unroll
    for (int it = 0; it < 16; ++it) {
      const int nn = (tid >> 6) + it * 4, kk = tid & 63;
      dst[(tj * 64 + nn) * HDIM + ti * 64 + kk] = (__bf16)tp[kk][nn];
    }
  }
  if (tid < NMODEL) lc[tid] = 0;
  __syncthreads();

  const int ppb   = (N + G - 1) / G;     // G>=256 -> ppb<=512 -> <=2 iters
  const int start = b * ppb;
  int myId[4], myRank[4];
  #pragma unroll
  for (int it = 0; it < 4; ++it) {
    const int o  = it * 256 + tid;
    const int pt = start + o;
    myId[it] = -1;
    if (o < ppb && pt < N) {
      myId[it] = model_of(x[3*pt], x[3*pt+1], x[3*pt+2]);
      myRank[it] = atomicAdd(&lc[myId[it]], 1);
    }
  }
  __syncthreads();
  if (tid < NMODEL) cntG[b * NMODEL + tid] = lc[tid];
  __threadfence();
  grid.sync();

  // ---- Phase B: redundant per-block prefix over cntG -> perm write ----
  if (tid < NMODEL) { pre_l[tid] = 0; tot_l[tid] = 0; }
  __syncthreads();
  {
    const int m = tid & 7;
    int tot = 0, pre = 0;
    for (int b2 = tid >> 3; b2 < G; b2 += 32) {
      const int v = cntG[b2 * NMODEL + m];
      tot += v;
      if (b2 < b) pre += v;
    }
    atomicAdd(&tot_l[m], tot);
    atomicAdd(&pre_l[m], pre);
  }
  __syncthreads();
  if (tid == 0) {
    int run = 0, trun = 0;
    for (int m = 0; m < NMODEL; ++m) {
      gb_l[m] = run;      run  += tot_l[m];
      tstart_l[m] = trun; trun += (tot_l[m] + TILE - 1) / TILE;
    }
    tstart_l[NMODEL] = trun;
  }
  __syncthreads();
  #pragma unroll
  for (int it = 0; it < 4; ++it)
    if (myId[it] >= 0)
      perm[gb_l[myId[it]] + pre_l[myId[it]] + myRank[it]] = start + it * 256 + tid;
  __threadfence();
  grid.sync();

  // ---- Phase C: tiled MFMA MLP ----
  const int lane = tid & 63;
  const int wave = tid >> 6;
  const int l16  = lane & 15;
  const int quad = lane >> 4;
  const int totTiles = tstart_l[NMODEL];

  for (int t = b; t < totTiles; t += G) {
    int m = 0;
    while (m < NMODEL - 1 && t >= tstart_l[m + 1]) ++m;
    const int lt   = t - tstart_l[m];
    const int base = gb_l[m] + lt * TILE;
    const int npts = min(TILE, tot_l[m] - lt * TILE);
    const __bf16* Wt1m = Wt1 + m * HDIM * HDIM;
    const __bf16* Wt2m = Wt2 + m * HDIM * HDIM;
    const float* W0m = W0 + m * 3 * HDIM;
    const float* b0m = b0 + m * HDIM;
    const float* b1m = b1 + m * HDIM;
    const float* b2m = b2 + m * HDIM;
    const float* W3m = W3 + m * HDIM;

    if (tid < TILE) {
      if (tid < npts) {
        const float mn0 = mins[3*m], mn1 = mins[3*m+1], mn2 = mins[3*m+2];
        const float mx0 = maxs[3*m], mx1 = maxs[3*m+1], mx2 = maxs[3*m+2];
        int p = perm[base + tid];
        pid[tid] = p;
        xs[tid][0] = -1.0f + 2.0f * (x[3*p]     - mn0) / (mx0 - mn0);
        xs[tid][1] = -1.0f + 2.0f * (x[3*p + 1] - mn1) / (mx1 - mn1);
        xs[tid][2] = -1.0f + 2.0f * (x[3*p + 2] - mn2) / (mx2 - mn2);
      } else {
        pid[tid] = -1;
        xs[tid][0] = 0.0f; xs[tid][1] = 0.0f; xs[tid][2] = 0.0f;
      }
    }
    __syncthreads();

    // layer 0: fp32 VALU, K=3 -> hA bf16 (weights from global, L1 broadcast)
    {
      const int p = tid & 63;
      const int j0 = (tid >> 6) * 32;
      const float xv0 = xs[p][0], xv1 = xs[p][1], xv2 = xs[p][2];
      #pragma unroll
      for (int j = j0; j < j0 + 32; j += 4) {
        bf16x4 pk;
        #pragma unroll
        for (int u = 0; u < 4; ++u) {
          float v = b0m[j+u] + xv0 * W0m[j+u] + xv1 * W0m[HDIM + j+u] + xv2 * W0m[2*HDIM + j+u];
          pk[u] = (__bf16)fmaxf(v, 0.0f);
        }
        *(bf16x4*)(hA + p * LDSH + j) = pk;
      }
    }
    __syncthreads();

    gemm_relu(hA, hB, Wt1m, b1m, wave, l16, quad);   // layer 1
    __syncthreads();
    gemm_relu(hB, hA, Wt2m, b2m, wave, l16, quad);   // layer 2
    __syncthreads();

    // layer 3: dot(h2, w3), 4 lanes/point
    {
      const int p = tid >> 2;
      const int part = tid & 3;
      float s = 0.0f;
      #pragma unroll
      for (int kk = 0; kk < 4; ++kk) {
        bf16x8 hv = *(const bf16x8*)(hA + p * LDSH + part * 32 + kk * 8);
        const float* wp = W3m + part * 32 + kk * 8;
        #pragma unroll
        for (int u = 0; u < 8; ++u) s += (float)hv[u] * wp[u];
      }
      s += __shfl_xor(s, 1);
      s += __shfl_xor(s, 2);
      if (part == 0 && p < npts) out[pid[p]] = s + b3[m];
    }
    __syncthreads();
  }
}

// ================= fallback (validated R2 pipeline) =================
__global__ __launch_bounds__(256)
void srn_prep_scatter(const float* __restrict__ W1, const float* __restrict__ W2,
                      const float* __restrict__ x,
                      __bf16* __restrict__ Wt1, __bf16* __restrict__ Wt2,
                      int* __restrict__ cursors, int* __restrict__ perm, int N)
{
  const int b = blockIdx.x;
  const int tid = threadIdx.x;
  if (b < 64) {
    __shared__ float lds[64][65];
    const int m   = b >> 3;
    const int r2  = b & 7;
    const int mat = r2 >> 2;
    const int ti  = (r2 >> 1) & 1;
    const int tj  = r2 & 1;
    const float* src = (mat ? W2 : W1) + m * HDIM * HDIM;
    __bf16*      dst = (mat ? Wt2 : Wt1) + m * HDIM * HDIM;
    #pragma unroll
    for (int it = 0; it < 16; ++it) {
      const int rr = (tid >> 6) + it * 4, cc = tid & 63;
      lds[rr][cc] = src[(ti * 64 + rr) * HDIM + tj * 64 + cc];
    }
    __syncthreads();
    #pragma unroll
    for (int it = 0; it < 16; ++it) {
      const int nn = (tid >> 6) + it * 4, kk = tid & 63;
      dst[(tj * 64 + nn) * HDIM + ti * 64 + kk] = (__bf16)lds[kk][nn];
    }
  } else {
    __shared__ int lc[NMODEL], lb[NMODEL];
    if (tid < NMODEL) lc[tid] = 0;
    __syncthreads();
    const int base = (b - 64) * 1024;
    int ids[4], rs[4];
    #pragma unroll
    for (int it = 0; it < 4; ++it) {
      const int i = base + it * 256 + tid;
      if (i < N) {
        ids[it] = model_of(x[3*i], x[3*i+1], x[3*i+2]);
        rs[it] = atomicAdd(&lc[ids[it]], 1);
      } else ids[it] = -1;
    }
    __syncthreads();
    if (tid < NMODEL) lb[tid] = lc[tid] ? atomicAdd(&cursors[tid], lc[tid]) : 0;
    __syncthreads();
    #pragma unroll
    for (int it = 0; it < 4; ++it) {
      const int i = base + it * 256 + tid;
      if (i < N) perm[ids[it] * N + lb[ids[it]] + rs[it]] = i;
    }
  }
}

__global__ __launch_bounds__(256, 4)
void srn_main(const float* __restrict__ x,
              const float* __restrict__ W0, const float* __restrict__ b0,
              const float* __restrict__ b1, const float* __restrict__ b2,
              const float* __restrict__ W3, const float* __restrict__ b3,
              const float* __restrict__ mins, const float* __restrict__ maxs,
              const __bf16* __restrict__ Wt1, const __bf16* __restrict__ Wt2,
              const int* __restrict__ cursors, const int* __restrict__ perm,
              float* __restrict__ out, int N)
{
  __shared__ __align__(16) __bf16 hA[TILE * LDSH];
  __shared__ __align__(16) __bf16 hB[TILE * LDSH];
  __shared__ float xs[TILE][3];
  __shared__ int   pid[TILE];

  const int m = blockIdx.y;
  const int tid = threadIdx.x;
  const int cnt = cursors[m];
  const int* permSeg = perm + (size_t)m * N;
  const float mn0 = mins[3*m], mn1 = mins[3*m+1], mn2 = mins[3*m+2];
  const float mx0 = maxs[3*m], mx1 = maxs[3*m+1], mx2 = maxs[3*m+2];
  const __bf16* Wt1m = Wt1 + m * HDIM * HDIM;
  const __bf16* Wt2m = Wt2 + m * HDIM * HDIM;
  const float* W0m = W0 + m * 3 * HDIM;
  const float* b0m = b0 + m * HDIM;
  const float* b1m = b1 + m * HDIM;
  const float* b2m = b2 + m * HDIM;
  const float* W3m = W3 + m * HDIM;
  const float b3v = b3[m];

  const int lane = tid & 63;
  const int wave = tid >> 6;
  const int l16  = lane & 15;
  const int quad = lane >> 4;

  for (int tile = blockIdx.x; tile * TILE < cnt; tile += gridDim.x) {
    const int base = tile * TILE;
    const int npts = min(TILE, cnt - base);
    if (tid < TILE) {
      if (tid < npts) {
        int p = permSeg[base + tid];
        pid[tid] = p;
        xs[tid][0] = -1.0f + 2.0f * (x[3*p]     - mn0) / (mx0 - mn0);
        xs[tid][1] = -1.0f + 2.0f * (x[3*p + 1] - mn1) / (mx1 - mn1);
        xs[tid][2] = -1.0f + 2.0f * (x[3*p + 2] - mn2) / (mx2 - mn2);
      } else {
        pid[tid] = -1;
        xs[tid][0] = 0.0f; xs[tid][1] = 0.0f; xs[tid][2] = 0.0f;
      }
    }
    __syncthreads();
    {
      const int p = tid & 63;
      const int j0 = (tid >> 6) * 32;
      const float xv0 = xs[p][0], xv1 = xs[p][1], xv2 = xs[p][2];
      #pragma unroll
      for (int j = j0; j < j0 + 32; j += 4) {
        bf16x4 pk;
        #pragma unroll
        for (int u = 0; u < 4; ++u) {
          float v = b0m[j+u] + xv0 * W0m[j+u] + xv1 * W0m[HDIM + j+u] + xv2 * W0m[2*HDIM + j+u];
          pk[u] = (__bf16)fmaxf(v, 0.0f);
        }
        *(bf16x4*)(hA + p * LDSH + j) = pk;
      }
    }
    __syncthreads();
    gemm_relu(hA, hB, Wt1m, b1m, wave, l16, quad);
    __syncthreads();
    gemm_relu(hB, hA, Wt2m, b2m, wave, l16, quad);
    __syncthreads();
    {
      const int p = tid >> 2;
      const int part = tid & 3;
      float s = 0.0f;
      #pragma unroll
      for (int kk = 0; kk < 4; ++kk) {
        bf16x8 hv = *(const bf16x8*)(hA + p * LDSH + part * 32 + kk * 8);
        const float* wp = W3m + part * 32 + kk * 8;
        #pragma unroll
        for (int u = 0; u < 8; ++u) s += (float)hv[u] * wp[u];
      }
      s += __shfl_xor(s, 1);
      s += __shfl_xor(s, 2);
      if (part == 0 && p < npts) out[pid[p]] = s + b3v;
    }
    __syncthreads();
  }
}

extern "C" void kernel_launch(void* const* d_in, const int* in_sizes, int n_in,
                              void* d_out, int out_size, void* d_ws, size_t ws_size,
                              hipStream_t stream)
{
  const float* x    = (const float*)d_in[0];
  const float* W0   = (const float*)d_in[1];
  const float* b0   = (const float*)d_in[2];
  const float* W1   = (const float*)d_in[3];
  const float* b1   = (const float*)d_in[4];
  const float* W2   = (const float*)d_in[5];
  const float* b2   = (const float*)d_in[6];
  const float* W3   = (const float*)d_in[7];
  const float* b3   = (const float*)d_in[8];
  const float* mins = (const float*)d_in[9];
  const float* maxs = (const float*)d_in[10];
  float* out = (float*)d_out;
  int N = in_sizes[0] / 3;

  char* ws = (char*)d_ws;
  int* cntG    = (int*)ws;                                // coop: [G][8]
  int* cursors = (int*)ws;                                // fallback: [8]
  int* perm    = (int*)(ws + 32768);                      // N ints (coop) / 8xN (fallback)
  __bf16* Wt1  = (__bf16*)(ws + 32768 + (size_t)4 * N * NMODEL);
  __bf16* Wt2  = Wt1 + NMODEL * HDIM * HDIM;

  // occupancy-clamped cooperative grid (host-side queries: graph-capture safe)
  int dev = 0;  hipGetDevice(&dev);
  int numCU = 0;
  hipDeviceGetAttribute(&numCU, hipDeviceAttributeMultiprocessorCount, dev);
  int occ = 0;
  hipOccupancyMaxActiveBlocksPerMultiprocessor(&occ, (const void*)srn_fused, 256, 0);
  int G = occ * numCU;
  if (G > MAXG) G = MAXG;

  hipError_t err = hipErrorUnknown;
  if (G >= 256) {
    void* args[] = { (void*)&x, (void*)&W0, (void*)&b0, (void*)&W1, (void*)&b1,
                     (void*)&W2, (void*)&b2, (void*)&W3, (void*)&b3,
                     (void*)&mins, (void*)&maxs, (void*)&cntG, (void*)&perm,
                     (void*)&Wt1, (void*)&Wt2, (void*)&out, (void*)&N };
    err = hipLaunchCooperativeKernel((const void*)srn_fused, dim3(G), dim3(256),
                                     args, 0, stream);
  }
  if (err != hipSuccess) {
    // validated R2 3-node fallback
    hipMemsetAsync(cursors, 0, NMODEL * sizeof(int), stream);
    const int sb = (N + 1023) >> 10;
    srn_prep_scatter<<<dim3(64 + sb), dim3(256), 0, stream>>>(W1, W2, x, Wt1, Wt2, cursors, perm, N);
    srn_main<<<dim3(TILES_X, NMODEL), dim3(256), 0, stream>>>(
        x, W0, b0, b1, b2, W3, b3, mins, maxs, Wt1, Wt2, cursors, perm, out, N);
  }
}

// Round 5
// 202.237 us; speedup vs baseline: 1.6484x; 1.6484x over previous
//
#include <hip/hip_runtime.h>
#include <hip/hip_bf16.h>

// Ensemble SRN: 8 sub-models (2x2x2 octants), MLP 3->128->128->128->1, ReLU.
// R5: back to the validated 2-kernel pipeline (grid.sync on gfx950 costs
// ~200us/sync at G=1024 — kernel boundaries are the cheap grid barrier).
//  node 1: srn_prep_scatter — weight transpose (blocks 0..63; block 0 also
//          zeroes cursors + sets ready flag) + point classify/normalize/
//          scatter into per-model float4{xn,pid} segments (blocks 64..).
//  node 2: srn_main — per-model 64-point-tile bf16 MFMA MLP.
// ws: [0,64)            cursors[8] + flag (cursors[8])
//     [64, 64+16*N*8)   xn segments: float4 per point, per-model capacity N
//     [.., +256KB)      Wt1 bf16 [8][128][128]  (transposed [n][k])
//     [.., +256KB)      Wt2 bf16 [8][128][128]

#define HDIM 128
#define LDSH 136      // padded LDS stride (bf16): 272B rows
#define TILE 64
#define NMODEL 8
#define TILES_X 272
#define SCAT_PPB 512
#define RDY_MAGIC 0x5AFE5AFE

typedef __bf16 bf16x8 __attribute__((ext_vector_type(8)));
typedef __bf16 bf16x4 __attribute__((ext_vector_type(4)));
typedef float  f32x4  __attribute__((ext_vector_type(4)));

__device__ __forceinline__ int model_of(float x0, float x1, float x2) {
  // match reference: u=(x+1)/(2+1e-6); cell=int(u_flipped*2); idx=c0+2c1+4c2
  const float den = 2.000001f;
  float u0 = (x0 + 1.0f) / den;
  float u1 = (x1 + 1.0f) / den;
  float u2 = (x2 + 1.0f) / den;
  int c0 = (int)(u2 * 2.0f);
  int c1 = (int)(u1 * 2.0f);
  int c2 = (int)(u0 * 2.0f);
  return c0 + (c1 << 1) + (c2 << 2);
}

// ---------- node 1: transpose + classify/normalize/scatter ----------
__global__ __launch_bounds__(256)
void srn_prep_scatter(const float* __restrict__ W1, const float* __restrict__ W2,
                      const float* __restrict__ x,
                      const float* __restrict__ mins, const float* __restrict__ maxs,
                      __bf16* __restrict__ Wt1, __bf16* __restrict__ Wt2,
                      int* __restrict__ cursors, f32x4* __restrict__ xn, int N)
{
  const int b   = blockIdx.x;
  const int tid = threadIdx.x;

  if (b < 64) {
    // block 0: zero cursors (device-scope) then publish ready flag
    if (b == 0) {
      if (tid < NMODEL) atomicExch(&cursors[tid], 0);
      __threadfence();
      if (tid == 0) atomicExch(&cursors[NMODEL], RDY_MAGIC);
    }
    // transpose one 64x64 fp32 tile -> bf16 Wt[n][k]
    __shared__ float lds[64][65];
    const int m   = b >> 3;
    const int r2  = b & 7;
    const int mat = r2 >> 2;
    const int ti  = (r2 >> 1) & 1;
    const int tj  = r2 & 1;
    const float* src = (mat ? W2 : W1) + m * HDIM * HDIM;
    __bf16*      dst = (mat ? Wt2 : Wt1) + m * HDIM * HDIM;
    #pragma unroll
    for (int it = 0; it < 16; ++it) {
      const int rr = (tid >> 6) + it * 4, cc = tid & 63;
      lds[rr][cc] = src[(ti * 64 + rr) * HDIM + tj * 64 + cc];
    }
    __syncthreads();
    #pragma unroll
    for (int it = 0; it < 16; ++it) {
      const int nn = (tid >> 6) + it * 4, kk = tid & 63;
      dst[(tj * 64 + nn) * HDIM + ti * 64 + kk] = (__bf16)lds[kk][nn];
    }
  } else {
    // classify 512 points (2/thread), then scatter normalized float4{xn,pid}
    __shared__ int lc[NMODEL], lb[NMODEL];
    if (tid < NMODEL) lc[tid] = 0;
    __syncthreads();
    const int base = (b - 64) * SCAT_PPB;
    int ids[2], rs[2];
    float px[2][3];
    #pragma unroll
    for (int it = 0; it < 2; ++it) {
      const int i = base + it * 256 + tid;
      ids[it] = -1;
      if (i < N) {
        px[it][0] = x[3*i]; px[it][1] = x[3*i+1]; px[it][2] = x[3*i+2];
        ids[it] = model_of(px[it][0], px[it][1], px[it][2]);
        rs[it] = atomicAdd(&lc[ids[it]], 1);
      }
    }
    __syncthreads();
    // wait until block 0 has zeroed the cursors (all blocks co-resident: grid
    // = 64 + N/512 = 320 blocks << capacity, so no deadlock)
    if (tid == 0) {
      while (atomicCAS(&cursors[NMODEL], RDY_MAGIC, RDY_MAGIC) != RDY_MAGIC) {
        __builtin_amdgcn_s_sleep(8);
      }
    }
    __syncthreads();
    if (tid < NMODEL) lb[tid] = lc[tid] ? atomicAdd(&cursors[tid], lc[tid]) : 0;
    __syncthreads();
    #pragma unroll
    for (int it = 0; it < 2; ++it) {
      if (ids[it] >= 0) {
        const int m = ids[it];
        const float mn0 = mins[3*m], mn1 = mins[3*m+1], mn2 = mins[3*m+2];
        const float mx0 = maxs[3*m], mx1 = maxs[3*m+1], mx2 = maxs[3*m+2];
        f32x4 v;
        v[0] = -1.0f + 2.0f * (px[it][0] - mn0) / (mx0 - mn0);
        v[1] = -1.0f + 2.0f * (px[it][1] - mn1) / (mx1 - mn1);
        v[2] = -1.0f + 2.0f * (px[it][2] - mn2) / (mx2 - mn2);
        v[3] = __int_as_float(base + it * 256 + tid);
        xn[(size_t)m * N + lb[m] + rs[it]] = v;
      }
    }
  }
}

// ---------- GEMM layer: hOut = relu(hIn @ W + b), [64x128]x[128x128] ----------
// wave w owns col-tiles {2w,2w+1}; bias read from global (L1-hot, wave-uniform).
__device__ __forceinline__ void gemm_relu(const __bf16* __restrict__ hIn,
                                          __bf16* __restrict__ hOut,
                                          const __bf16* __restrict__ Wt,
                                          const float* __restrict__ bias,
                                          int wave, int l16, int quad)
{
  const int n0 = wave * 32;
  f32x4 acc[4][2] = {};
  #pragma unroll
  for (int kk = 0; kk < 4; ++kk) {
    const int kOff = kk * 32 + quad * 8;
    bf16x8 bv0 = *(const bf16x8*)(Wt + (n0 + l16) * HDIM + kOff);
    bf16x8 bv1 = *(const bf16x8*)(Wt + (n0 + 16 + l16) * HDIM + kOff);
    #pragma unroll
    for (int r = 0; r < 4; ++r) {
      bf16x8 av = *(const bf16x8*)(hIn + (r * 16 + l16) * LDSH + kOff);
      acc[r][0] = __builtin_amdgcn_mfma_f32_16x16x32_bf16(av, bv0, acc[r][0], 0, 0, 0);
      acc[r][1] = __builtin_amdgcn_mfma_f32_16x16x32_bf16(av, bv1, acc[r][1], 0, 0, 0);
    }
  }
  const float bv0 = bias[n0 + l16];
  const float bv1 = bias[n0 + 16 + l16];
  #pragma unroll
  for (int r = 0; r < 4; ++r) {
    #pragma unroll
    for (int c = 0; c < 2; ++c) {
      const int n = n0 + c * 16 + l16;
      const float bb = c ? bv1 : bv0;
      #pragma unroll
      for (int i = 0; i < 4; ++i) {
        const int row = r * 16 + quad * 4 + i;   // C/D: col=lane&15, row=quad*4+reg
        float v = acc[r][c][i] + bb;
        hOut[row * LDSH + n] = (__bf16)fmaxf(v, 0.0f);
      }
    }
  }
}

// ---------- node 2: per-model tiled MFMA MLP ----------
__global__ __launch_bounds__(256, 4)
void srn_main(const float* __restrict__ W0, const float* __restrict__ b0,
              const float* __restrict__ b1, const float* __restrict__ b2,
              const float* __restrict__ W3, const float* __restrict__ b3,
              const __bf16* __restrict__ Wt1, const __bf16* __restrict__ Wt2,
              const int* __restrict__ cursors, const f32x4* __restrict__ xn,
              float* __restrict__ out, int N)
{
  __shared__ __align__(16) __bf16 hA[TILE * LDSH];
  __shared__ __align__(16) __bf16 hB[TILE * LDSH];
  __shared__ float xs[TILE][3];
  __shared__ int   pid[TILE];

  const int m   = blockIdx.y;
  const int tid = threadIdx.x;
  const int cnt = cursors[m];
  const f32x4* xnSeg = xn + (size_t)m * N;
  const __bf16* Wt1m = Wt1 + m * HDIM * HDIM;
  const __bf16* Wt2m = Wt2 + m * HDIM * HDIM;
  const float* W0m = W0 + m * 3 * HDIM;
  const float* b0m = b0 + m * HDIM;
  const float* b1m = b1 + m * HDIM;
  const float* b2m = b2 + m * HDIM;
  const float* W3m = W3 + m * HDIM;
  const float b3v = b3[m];

  const int lane = tid & 63;
  const int wave = tid >> 6;
  const int l16  = lane & 15;
  const int quad = lane >> 4;

  for (int tile = blockIdx.x; tile * TILE < cnt; tile += gridDim.x) {
    const int base = tile * TILE;
    const int npts = min(TILE, cnt - base);

    if (tid < TILE) {
      f32x4 v = xnSeg[base + tid];          // coalesced 16B/lane
      if (tid < npts) {
        pid[tid] = __float_as_int(v[3]);
        xs[tid][0] = v[0]; xs[tid][1] = v[1]; xs[tid][2] = v[2];
      } else {
        pid[tid] = -1;
        xs[tid][0] = 0.0f; xs[tid][1] = 0.0f; xs[tid][2] = 0.0f;
      }
    }
    __syncthreads();

    // layer 0: fp32 VALU, K=3 -> hA bf16 (W0/b0 global, wave-uniform broadcast)
    {
      const int p = tid & 63;
      const int j0 = (tid >> 6) * 32;
      const float xv0 = xs[p][0], xv1 = xs[p][1], xv2 = xs[p][2];
      #pragma unroll
      for (int j = j0; j < j0 + 32; j += 4) {
        bf16x4 pk;
        #pragma unroll
        for (int u = 0; u < 4; ++u) {
          float v = b0m[j+u] + xv0 * W0m[j+u] + xv1 * W0m[HDIM + j+u] + xv2 * W0m[2*HDIM + j+u];
          pk[u] = (__bf16)fmaxf(v, 0.0f);
        }
        *(bf16x4*)(hA + p * LDSH + j) = pk;
      }
    }
    __syncthreads();

    gemm_relu(hA, hB, Wt1m, b1m, wave, l16, quad);   // layer 1
    __syncthreads();
    gemm_relu(hB, hA, Wt2m, b2m, wave, l16, quad);   // layer 2
    __syncthreads();

    // layer 3: dot(h2, w3), 4 lanes/point
    {
      const int p = tid >> 2;
      const int part = tid & 3;
      float s = 0.0f;
      #pragma unroll
      for (int kk = 0; kk < 4; ++kk) {
        bf16x8 hv = *(const bf16x8*)(hA + p * LDSH + part * 32 + kk * 8);
        const float* wp = W3m + part * 32 + kk * 8;
        #pragma unroll
        for (int u = 0; u < 8; ++u) s += (float)hv[u] * wp[u];
      }
      s += __shfl_xor(s, 1);
      s += __shfl_xor(s, 2);
      if (part == 0 && p < npts) out[pid[p]] = s + b3v;
    }
    __syncthreads();
  }
}

extern "C" void kernel_launch(void* const* d_in, const int* in_sizes, int n_in,
                              void* d_out, int out_size, void* d_ws, size_t ws_size,
                              hipStream_t stream)
{
  const float* x    = (const float*)d_in[0];
  const float* W0   = (const float*)d_in[1];
  const float* b0   = (const float*)d_in[2];
  const float* W1   = (const float*)d_in[3];
  const float* b1   = (const float*)d_in[4];
  const float* W2   = (const float*)d_in[5];
  const float* b2   = (const float*)d_in[6];
  const float* W3   = (const float*)d_in[7];
  const float* b3   = (const float*)d_in[8];
  const float* mins = (const float*)d_in[9];
  const float* maxs = (const float*)d_in[10];
  float* out = (float*)d_out;
  int N = in_sizes[0] / 3;

  char* ws = (char*)d_ws;
  int*   cursors = (int*)ws;                              // [0,64): cursors[8]+flag
  f32x4* xn      = (f32x4*)(ws + 64);                     // 8 segments x N float4
  __bf16* Wt1    = (__bf16*)(ws + 64 + (size_t)16 * N * NMODEL);
  __bf16* Wt2    = Wt1 + NMODEL * HDIM * HDIM;

  const int sb = (N + SCAT_PPB - 1) / SCAT_PPB;
  srn_prep_scatter<<<dim3(64 + sb), dim3(256), 0, stream>>>(
      W1, W2, x, mins, maxs, Wt1, Wt2, cursors, xn, N);
  srn_main<<<dim3(TILES_X, NMODEL), dim3(256), 0, stream>>>(
      W0, b0, b1, b2, W3, b3, Wt1, Wt2, cursors, xn, out, N);
}

// Round 6
// 112.405 us; speedup vs baseline: 2.9658x; 1.7992x over previous
//
#include <hip/hip_runtime.h>
#include <hip/hip_bf16.h>

// Ensemble SRN: 8 sub-models (2x2x2 octants), MLP 3->128->128->128->1, ReLU.
// R6: 2-kernel pipeline, REGISTER-RESIDENT weights.
//  node 1: srn_scatter — classify/normalize points into per-model float4
//          {xn0,xn1,xn2,pid} segments (block 0 zeroes cursors, flag-spin).
//  node 2: srn_main — grid 64x8; each wave preloads its 32-col slice of
//          W1 AND W2 as bf16 MFMA B-fragments (64 VGPRs) once per block,
//          straight from fp32 d_in (L2/L3-warm, never poisoned). Per tile:
//          layer0 VALU -> LDS, 2 MFMA gemms (B from registers), layer3 dot.
// Lesson bank: grid.sync ~200us at G=1024 (R4); per-tile global Wt reads =
// 134 MB HBM stream after ws poison (R5). ws only holds cursors + xn now.
// ws: [0,64)           cursors[8] + ready flag
//     [64, 64+16*N*8)  xn segments: float4 per point, per-model capacity N

#define HDIM 128
#define LDSH 136      // padded LDS stride (bf16): 272B rows -> 2-way alias (free)
#define TILE 64
#define NMODEL 8
#define GB 64         // blocks per model; grid 512 = 2 blocks/CU
#define SCAT_PPB 512
#define RDY_MAGIC 0x5AFE5AFE

typedef __bf16 bf16x8 __attribute__((ext_vector_type(8)));
typedef __bf16 bf16x4 __attribute__((ext_vector_type(4)));
typedef float  f32x4  __attribute__((ext_vector_type(4)));

__device__ __forceinline__ int model_of(float x0, float x1, float x2) {
  // match reference: u=(x+1)/(2+1e-6); cell=int(u_flipped*2); idx=c0+2c1+4c2
  const float den = 2.000001f;
  float u0 = (x0 + 1.0f) / den;
  float u1 = (x1 + 1.0f) / den;
  float u2 = (x2 + 1.0f) / den;
  int c0 = (int)(u2 * 2.0f);
  int c1 = (int)(u1 * 2.0f);
  int c2 = (int)(u0 * 2.0f);
  return c0 + (c1 << 1) + (c2 << 2);
}

// ---------- node 1: classify + normalize + scatter ----------
__global__ __launch_bounds__(256)
void srn_scatter(const float* __restrict__ x,
                 const float* __restrict__ mins, const float* __restrict__ maxs,
                 int* __restrict__ cursors, f32x4* __restrict__ xn, int N)
{
  __shared__ int lc[NMODEL], lb[NMODEL];
  const int b   = blockIdx.x;
  const int tid = threadIdx.x;
  if (tid < NMODEL) lc[tid] = 0;
  __syncthreads();

  const int base = b * SCAT_PPB;
  int ids[2], rs[2];
  float px[2][3];
  #pragma unroll
  for (int it = 0; it < 2; ++it) {
    const int i = base + it * 256 + tid;
    ids[it] = -1;
    if (i < N) {
      px[it][0] = x[3*i]; px[it][1] = x[3*i+1]; px[it][2] = x[3*i+2];
      ids[it] = model_of(px[it][0], px[it][1], px[it][2]);
      rs[it] = atomicAdd(&lc[ids[it]], 1);
    }
  }
  __syncthreads();

  // block 0 zeroes the poisoned cursors, then publishes the ready flag;
  // all other blocks spin (grid = N/512 = 256 blocks -> all co-resident).
  if (b == 0) {
    if (tid < NMODEL) atomicExch(&cursors[tid], 0);
    __threadfence();
    if (tid == 0) atomicExch(&cursors[NMODEL], RDY_MAGIC);
  } else if (tid == 0) {
    while (atomicCAS(&cursors[NMODEL], RDY_MAGIC, RDY_MAGIC) != RDY_MAGIC) {
      __builtin_amdgcn_s_sleep(8);
    }
  }
  __syncthreads();
  if (tid < NMODEL) lb[tid] = lc[tid] ? atomicAdd(&cursors[tid], lc[tid]) : 0;
  __syncthreads();

  #pragma unroll
  for (int it = 0; it < 2; ++it) {
    if (ids[it] >= 0) {
      const int m = ids[it];
      const float mn0 = mins[3*m], mn1 = mins[3*m+1], mn2 = mins[3*m+2];
      const float mx0 = maxs[3*m], mx1 = maxs[3*m+1], mx2 = maxs[3*m+2];
      f32x4 v;
      v[0] = -1.0f + 2.0f * (px[it][0] - mn0) / (mx0 - mn0);
      v[1] = -1.0f + 2.0f * (px[it][1] - mn1) / (mx1 - mn1);
      v[2] = -1.0f + 2.0f * (px[it][2] - mn2) / (mx2 - mn2);
      v[3] = __int_as_float(base + it * 256 + tid);
      xn[(size_t)m * N + lb[m] + rs[it]] = v;
    }
  }
}

// ---------- GEMM layer with register-resident B ----------
// hOut = relu(hIn @ W + b); wave owns cols [n0, n0+32).
__device__ __forceinline__ void gemm_reg(const __bf16* __restrict__ hIn,
                                         __bf16* __restrict__ hOut,
                                         const bf16x8 (&wr)[4][2],
                                         const float* __restrict__ biasS,
                                         int n0, int l16, int quad)
{
  f32x4 acc[4][2] = {};
  #pragma unroll
  for (int kk = 0; kk < 4; ++kk) {
    const int kOff = kk * 32 + quad * 8;
    #pragma unroll
    for (int r = 0; r < 4; ++r) {
      bf16x8 av = *(const bf16x8*)(hIn + (r * 16 + l16) * LDSH + kOff);
      acc[r][0] = __builtin_amdgcn_mfma_f32_16x16x32_bf16(av, wr[kk][0], acc[r][0], 0, 0, 0);
      acc[r][1] = __builtin_amdgcn_mfma_f32_16x16x32_bf16(av, wr[kk][1], acc[r][1], 0, 0, 0);
    }
  }
  const float bv0 = biasS[n0 + l16];
  const float bv1 = biasS[n0 + 16 + l16];
  #pragma unroll
  for (int r = 0; r < 4; ++r) {
    #pragma unroll
    for (int c = 0; c < 2; ++c) {
      const int n = n0 + c * 16 + l16;
      const float bb = c ? bv1 : bv0;
      #pragma unroll
      for (int i = 0; i < 4; ++i) {
        const int row = r * 16 + quad * 4 + i;   // C/D: col=lane&15, row=quad*4+reg
        float v = acc[r][c][i] + bb;
        hOut[row * LDSH + n] = (__bf16)fmaxf(v, 0.0f);
      }
    }
  }
}

// ---------- node 2: per-model tiled MFMA MLP, weights in registers ----------
__global__ __launch_bounds__(256, 2)
void srn_main(const float* __restrict__ W0, const float* __restrict__ b0,
              const float* __restrict__ W1, const float* __restrict__ b1,
              const float* __restrict__ W2, const float* __restrict__ b2,
              const float* __restrict__ W3, const float* __restrict__ b3,
              const int* __restrict__ cursors, const f32x4* __restrict__ xn,
              float* __restrict__ out, int N)
{
  __shared__ __align__(16) __bf16 hA[TILE * LDSH];
  __shared__ __align__(16) __bf16 hB[TILE * LDSH];
  __shared__ float xs[TILE][3];
  __shared__ int   pid[TILE];
  __shared__ float w0s[3 * HDIM];
  __shared__ float b0s[HDIM], b1s[HDIM], b2s[HDIM], w3s[HDIM];

  const int m   = blockIdx.y;
  const int tid = threadIdx.x;
  const int lane = tid & 63;
  const int wave = tid >> 6;
  const int l16  = lane & 15;
  const int quad = lane >> 4;
  const int n0   = wave * 32;

  // stage small per-model vectors in LDS (once per block)
  if (tid < HDIM) {
    const float* W0m = W0 + m * 3 * HDIM;
    w0s[tid]          = W0m[tid];
    w0s[HDIM + tid]   = W0m[HDIM + tid];
    w0s[2*HDIM + tid] = W0m[2*HDIM + tid];
    b0s[tid] = b0[m * HDIM + tid];
    b1s[tid] = b1[m * HDIM + tid];
    b2s[tid] = b2[m * HDIM + tid];
    w3s[tid] = W3[m * HDIM + tid];
  }

  // preload this wave's B-fragments for W1 and W2 into registers (64 VGPRs).
  // W1/W2 are [k][n] fp32 (original layout); B-frag lane element u is
  // B[k = kk*32 + quad*8 + u][n = n0 + c*16 + l16].
  const float* W1m = W1 + m * HDIM * HDIM;
  const float* W2m = W2 + m * HDIM * HDIM;
  bf16x8 w1r[4][2], w2r[4][2];
  #pragma unroll
  for (int kk = 0; kk < 4; ++kk) {
    #pragma unroll
    for (int c = 0; c < 2; ++c) {
      const int off = (kk * 32 + quad * 8) * HDIM + n0 + c * 16 + l16;
      bf16x8 v1, v2;
      #pragma unroll
      for (int u = 0; u < 8; ++u) {
        v1[u] = (__bf16)W1m[off + u * HDIM];
        v2[u] = (__bf16)W2m[off + u * HDIM];
      }
      w1r[kk][c] = v1;
      w2r[kk][c] = v2;
    }
  }

  const int cnt = cursors[m];
  const f32x4* xnSeg = xn + (size_t)m * N;
  const float b3v = b3[m];
  __syncthreads();

  for (int tile = blockIdx.x; tile * TILE < cnt; tile += GB) {
    const int base = tile * TILE;
    const int npts = min(TILE, cnt - base);

    if (tid < TILE) {
      f32x4 v = xnSeg[base + tid];          // coalesced 16B/lane
      if (tid < npts) {
        pid[tid] = __float_as_int(v[3]);
        xs[tid][0] = v[0]; xs[tid][1] = v[1]; xs[tid][2] = v[2];
      } else {
        pid[tid] = -1;
        xs[tid][0] = 0.0f; xs[tid][1] = 0.0f; xs[tid][2] = 0.0f;
      }
    }
    __syncthreads();

    // layer 0: fp32 VALU, K=3 -> hA bf16
    {
      const int p = lane;
      const int j0 = wave * 32;
      const float xv0 = xs[p][0], xv1 = xs[p][1], xv2 = xs[p][2];
      #pragma unroll
      for (int j = j0; j < j0 + 32; j += 4) {
        bf16x4 pk;
        #pragma unroll
        for (int u = 0; u < 4; ++u) {
          float v = b0s[j+u] + xv0 * w0s[j+u] + xv1 * w0s[HDIM + j+u] + xv2 * w0s[2*HDIM + j+u];
          pk[u] = (__bf16)fmaxf(v, 0.0f);
        }
        *(bf16x4*)(hA + p * LDSH + j) = pk;
      }
    }
    __syncthreads();

    gemm_reg(hA, hB, w1r, b1s, n0, l16, quad);   // layer 1
    __syncthreads();
    gemm_reg(hB, hA, w2r, b2s, n0, l16, quad);   // layer 2
    __syncthreads();

    // layer 3: dot(h2, w3), 4 lanes/point
    {
      const int p = tid >> 2;
      const int part = tid & 3;
      float s = 0.0f;
      #pragma unroll
      for (int kk = 0; kk < 4; ++kk) {
        bf16x8 hv = *(const bf16x8*)(hA + p * LDSH + part * 32 + kk * 8);
        const float* wp = w3s + part * 32 + kk * 8;
        #pragma unroll
        for (int u = 0; u < 8; ++u) s += (float)hv[u] * wp[u];
      }
      s += __shfl_xor(s, 1);
      s += __shfl_xor(s, 2);
      if (part == 0 && p < npts) out[pid[p]] = s + b3v;
    }
    __syncthreads();
  }
}

extern "C" void kernel_launch(void* const* d_in, const int* in_sizes, int n_in,
                              void* d_out, int out_size, void* d_ws, size_t ws_size,
                              hipStream_t stream)
{
  const float* x    = (const float*)d_in[0];
  const float* W0   = (const float*)d_in[1];
  const float* b0   = (const float*)d_in[2];
  const float* W1   = (const float*)d_in[3];
  const float* b1   = (const float*)d_in[4];
  const float* W2   = (const float*)d_in[5];
  const float* b2   = (const float*)d_in[6];
  const float* W3   = (const float*)d_in[7];
  const float* b3   = (const float*)d_in[8];
  const float* mins = (const float*)d_in[9];
  const float* maxs = (const float*)d_in[10];
  float* out = (float*)d_out;
  int N = in_sizes[0] / 3;

  char* ws = (char*)d_ws;
  int*   cursors = (int*)ws;            // [0,64): cursors[8] + ready flag
  f32x4* xn      = (f32x4*)(ws + 64);   // 8 segments x N float4

  const int sb = (N + SCAT_PPB - 1) / SCAT_PPB;
  srn_scatter<<<dim3(sb), dim3(256), 0, stream>>>(x, mins, maxs, cursors, xn, N);
  srn_main<<<dim3(GB, NMODEL), dim3(256), 0, stream>>>(
      W0, b0, W1, b1, W2, b2, W3, b3, cursors, xn, out, N);
}